// Round 1
// baseline (241.682 us; speedup 1.0000x reference)
//
#include <hip/hip_runtime.h>
#include <cstddef>

// RNN: h_t = tanh(x_t @ W_ih^T + b_ih + h_{t-1} @ W_hh^T + b_hh), return h_T.
// B=4096, T=512, IN=15, H=20. fp32 throughout (no fp32 MFMA on CDNA4; bf16
// recurrence would exceed the error threshold).
//
// Mapping: lane = g*20 + j ; g in 0..2 = batch group within wave, j = hidden
// unit. 3 batches / wave, 64-thread (1-wave) blocks -> no barriers needed:
// LDS ops from a single wave are in program order (wave-synchronous h swap).
// Each lane keeps W_ih row j (15) and W_hh row j (20) in registers; only h
// is shared via LDS (5x ds_read_b128 broadcast / step).
// feature is staged through LDS in 32-timestep double-buffered chunks:
// coalesced loads for chunk c+1 issue before computing chunk c (~3800 cyc of
// compute hides ~900 cyc HBM miss latency at our low 1.3 waves/SIMD).

typedef float g4 __attribute__((ext_vector_type(4), aligned(4)));  // 4B-aligned global vec
typedef float g2 __attribute__((ext_vector_type(2), aligned(4)));
typedef float v4 __attribute__((ext_vector_type(4)));
typedef float f2 __attribute__((ext_vector_type(2)));

#define TT 512
#define IN 15
#define HD 20
#define CH 32            // timesteps per staged chunk
#define NCH (TT / CH)    // 16 chunks

__device__ __forceinline__ f2 lo2(v4 v) { return (f2){v.x, v.y}; }
__device__ __forceinline__ f2 hi2(v4 v) { return (f2){v.z, v.w}; }

__global__ __launch_bounds__(64) void rnn_fused(
    const float* __restrict__ feature, const float* __restrict__ W_ih,
    const float* __restrict__ W_hh, const float* __restrict__ b_ih,
    const float* __restrict__ b_hh, float* __restrict__ out, int B) {
  // x chunk buffer: [dbuf][group][timestep][16] (15 floats + zero pad at [15])
  __shared__ float xb[2][3][CH][16];
  // h state: rows 0..2 real groups, row 3 = dummy lanes 60..63 sandbox
  __shared__ float hl[4][HD];

  const int lane = threadIdx.x;        // 0..63
  const int g = lane / HD;             // 0..3 (3 = dummy)
  const int j = lane - g * HD;         // 0..19
  const int gx = (g < 3) ? g : 2;      // clamp dummy lanes to a valid x row
  const int bid = blockIdx.x;
  const int b = bid * 3 + g;

  // h0 = 0 for all rows (incl. dummy row 3); zero the x pad slots once.
  for (int i = lane; i < 4 * HD; i += 64) ((float*)hl)[i] = 0.f;
  for (int i = lane; i < 2 * 3 * CH; i += 64) ((float*)xb)[i * 16 + 15] = 0.f;

  // Per-lane weight rows (lane only ever needs row j) packed as float2 for
  // v_pk_fma_f32. wih[7].y = 0 pairs with the x pad element.
  f2 wih[8];
  {
    const float* wr = W_ih + j * IN;
#pragma unroll
    for (int i = 0; i < 7; ++i) wih[i] = (f2){wr[2 * i], wr[2 * i + 1]};
    wih[7] = (f2){wr[14], 0.f};
  }
  f2 whh[10];
  {
    const float* wr = W_hh + j * HD;
#pragma unroll
    for (int i = 0; i < 10; ++i) whh[i] = (f2){wr[2 * i], wr[2 * i + 1]};
  }
  const float bias = b_ih[j] + b_hh[j];

  // ---- chunk staging: 96 rows of 60B per chunk (3 groups x 32 timesteps).
  // Row r: g=r>>5, t=r&31. Lane L loads row L; lanes<32 also load row 64+L.
  const int grA = lane >> 5;           // 0 or 1
  const int tcA = lane & 31;
  const int bc = B - 1;
  const int bA = min(bid * 3 + grA, bc);
  const int bB = min(bid * 3 + 2, bc);
  const float* baseA = feature + ((size_t)bA * TT + tcA) * IN;
  const float* baseB = feature + ((size_t)bB * TT + tcA) * IN;  // lanes<32 only

  g4 rA0, rA1, rA2; g2 rA3; float rA4;
  g4 rB0, rB1, rB2; g2 rB3; float rB4;

  auto issue = [&](int t0) {  // coalesced global loads into regs (no use yet)
    const float* s = baseA + (size_t)t0 * IN;
    rA0 = *(const g4*)(s);      rA1 = *(const g4*)(s + 4);
    rA2 = *(const g4*)(s + 8);  rA3 = *(const g2*)(s + 12);
    rA4 = s[14];
    if (lane < 32) {
      const float* s2 = baseB + (size_t)t0 * IN;
      rB0 = *(const g4*)(s2);     rB1 = *(const g4*)(s2 + 4);
      rB2 = *(const g4*)(s2 + 8); rB3 = *(const g2*)(s2 + 12);
      rB4 = s2[14];
    }
  };
  auto commit = [&](int bsel) {  // regs -> LDS (vmcnt wait lands here)
    float* d = &xb[bsel][grA][tcA][0];
    *(v4*)d = (v4)rA0; *(v4*)(d + 4) = (v4)rA1; *(v4*)(d + 8) = (v4)rA2;
    *(f2*)(d + 12) = (f2)rA3; d[14] = rA4;
    if (lane < 32) {
      float* d2 = &xb[bsel][2][tcA][0];
      *(v4*)d2 = (v4)rB0; *(v4*)(d2 + 4) = (v4)rB1; *(v4*)(d2 + 8) = (v4)rB2;
      *(f2*)(d2 + 12) = (f2)rB3; d2[14] = rB4;
    }
  };

  issue(0);
  commit(0);

  float hn = 0.f;
  const float* hrow = &hl[g][0];
  float* hwr = &hl[g][j];
  for (int c = 0; c < NCH; ++c) {
    if (c + 1 < NCH) issue((c + 1) * CH);   // prefetch next chunk
    const float* xrow = &xb[c & 1][gx][0][0];
#pragma unroll 4
    for (int tc = 0; tc < CH; ++tc) {
      const v4* xp = (const v4*)(xrow + tc * 16);
      v4 x0 = xp[0], x1 = xp[1], x2 = xp[2], x3 = xp[3];   // 4x ds_read_b128
      const v4* hp = (const v4*)hrow;
      v4 h0 = hp[0], h1 = hp[1], h2 = hp[2], h3 = hp[3], h4 = hp[4];  // 5x b128 broadcast
      f2 a0 = (f2){bias, 0.f}, a1 = (f2){0.f, 0.f};
      f2 a2 = (f2){0.f, 0.f},  a3 = (f2){0.f, 0.f};
      // x projection (8 packed FMAs; pad*0 via wih[7].y)
      a0 += lo2(x0) * wih[0]; a1 += hi2(x0) * wih[1];
      a2 += lo2(x1) * wih[2]; a3 += hi2(x1) * wih[3];
      a0 += lo2(x2) * wih[4]; a1 += hi2(x2) * wih[5];
      a2 += lo2(x3) * wih[6]; a3 += hi2(x3) * wih[7];
      // recurrent projection (10 packed FMAs)
      a0 += lo2(h0) * whh[0]; a1 += hi2(h0) * whh[1];
      a2 += lo2(h1) * whh[2]; a3 += hi2(h1) * whh[3];
      a0 += lo2(h2) * whh[4]; a1 += hi2(h2) * whh[5];
      a2 += lo2(h3) * whh[6]; a3 += hi2(h3) * whh[7];
      a0 += lo2(h4) * whh[8]; a1 += hi2(h4) * whh[9];
      f2 sv = (a0 + a1) + (a2 + a3);
      float s = sv.x + sv.y;
      // tanh(s) = 1 - 2/(1+e^{2s});  e^{2s} = exp2(s * 2*log2(e))
      float e = exp2f(s * 2.8853900817779268f);
      hn = 1.f - 2.f * __builtin_amdgcn_rcpf(1.f + e);
      *hwr = hn;  // same-wave LDS: in-order DS pipe, no barrier needed
    }
    if (c + 1 < NCH) commit((c + 1) & 1);
  }
  if (g < 3 && b < B) out[(size_t)b * HD + j] = hn;
}

extern "C" void kernel_launch(void* const* d_in, const int* in_sizes, int n_in,
                              void* d_out, int out_size, void* d_ws, size_t ws_size,
                              hipStream_t stream) {
  const float* feature = (const float*)d_in[0];
  const float* W_ih    = (const float*)d_in[1];
  const float* W_hh    = (const float*)d_in[2];
  const float* b_ih    = (const float*)d_in[3];
  const float* b_hh    = (const float*)d_in[4];
  float* out = (float*)d_out;
  const int B = in_sizes[0] / (TT * IN);      // 4096
  const int grid = (B + 2) / 3;               // 3 batches per 64-thread block
  rnn_fused<<<grid, 64, 0, stream>>>(feature, W_ih, W_hh, b_ih, b_hh, out, B);
}

// Round 2
// 233.622 us; speedup vs baseline: 1.0345x; 1.0345x over previous
//
#include <hip/hip_runtime.h>
#include <cstddef>

// RNN: h_t = tanh(x_t @ W_ih^T + b_ih + h_{t-1} @ W_hh^T + b_hh), return h_T.
// B=4096, T=512, IN=15, H=20.
//
// R0 post-mortem: LDS-pipe-throughput-bound (9x ds_read_b128 + 1 write per
// step per wave ~ 570 DS cyc/CU/step == measured 562 cyc/step wall), plus
// 3-way bank conflicts on x reads (group stride was 0 mod 32 banks).
// R1: f16 data plane. x staged as f16 (16 halves/row incl. zero pad -> 2x
// ds_read_b128), h exchanged as f16 (20 halves -> b128+b128+b64), dots via
// v_dot2_f32_f16 (f32 accumulate). Group strides padded so the 3 batch
// groups' rows land on disjoint banks. DS/step: 10 ops -> 6.
//
// Mapping unchanged: lane = g*20 + j, 3 batches per 64-thread (1-wave)
// block -> wave-synchronous LDS h swap, zero barriers.

typedef float g4 __attribute__((ext_vector_type(4), aligned(4)));
typedef float g2 __attribute__((ext_vector_type(2), aligned(4)));
typedef _Float16 h2  __attribute__((ext_vector_type(2)));
typedef _Float16 v8h __attribute__((ext_vector_type(8)));
typedef _Float16 v4h __attribute__((ext_vector_type(4)));

#define TT 512
#define IN 15
#define HD 20
#define CH 32                 // timesteps per staged chunk
#define NCH (TT / CH)         // 16 chunks
#define XROW 16               // halves per x row (15 + zero pad)
#define XGRP (CH * XROW + 16) // 528 halves: +16 pad -> group bases 8 banks apart
#define XBUF (3 * XGRP)       // 1584 halves per dbuf
#define HROW 24               // halves per h row -> rows 12 dwords apart (banks 0/12/24/4)

#define P2(v, i) __builtin_shufflevector(v, v, 2 * (i), 2 * (i) + 1)
#define FD(acc, p, w) acc = __builtin_amdgcn_fdot2(p, w, acc, false)

__global__ __launch_bounds__(64) void rnn_fused(
    const float* __restrict__ feature, const float* __restrict__ W_ih,
    const float* __restrict__ W_hh, const float* __restrict__ b_ih,
    const float* __restrict__ b_hh, float* __restrict__ out, int B) {
  __shared__ __align__(16) _Float16 xh[2 * XBUF];
  __shared__ __align__(16) _Float16 hh[4 * HROW];

  const int lane = threadIdx.x;        // 0..63
  const int g = lane / HD;             // 0..3 (3 = dummy lanes 60..63)
  const int j = lane - g * HD;         // 0..19
  const int gx = (g < 3) ? g : 2;      // dummy lanes read a valid x row
  const int bid = blockIdx.x;
  const int b = bid * 3 + g;

  // h0 = 0 for all 4 rows (96 halves = 48 dwords).
  if (lane < 48) ((float*)hh)[lane] = 0.f;

  // Per-lane weight rows in f16 pairs for v_dot2_f32_f16. wih[7].y = 0 pairs
  // with the zero pad half at x[15].
  h2 wih[8];
  {
    const float* wr = W_ih + j * IN;
#pragma unroll
    for (int i = 0; i < 7; ++i)
      wih[i] = (h2){(_Float16)wr[2 * i], (_Float16)wr[2 * i + 1]};
    wih[7] = (h2){(_Float16)wr[14], (_Float16)0.f};
  }
  h2 whh[10];
  {
    const float* wr = W_hh + j * HD;
#pragma unroll
    for (int i = 0; i < 10; ++i)
      whh[i] = (h2){(_Float16)wr[2 * i], (_Float16)wr[2 * i + 1]};
  }
  const float bias = b_ih[j] + b_hh[j];   // bias stays f32 (acc init)

  // ---- chunk staging: 96 rows (3 groups x 32 t) of 15 f32 -> 16 f16.
  const int grA = lane >> 5;           // 0 or 1
  const int tcA = lane & 31;
  const int bc = B - 1;
  const int bA = min(bid * 3 + grA, bc);
  const int bB = min(bid * 3 + 2, bc);
  const float* baseA = feature + ((size_t)bA * TT + tcA) * IN;
  const float* baseB = feature + ((size_t)bB * TT + tcA) * IN;  // lanes<32

  g4 rA0, rA1, rA2; g2 rA3; float rA4;
  g4 rB0, rB1, rB2; g2 rB3; float rB4;

  auto issue = [&](int t0) {  // coalesced f32 global loads into regs
    const float* s = baseA + (size_t)t0 * IN;
    rA0 = *(const g4*)(s);      rA1 = *(const g4*)(s + 4);
    rA2 = *(const g4*)(s + 8);  rA3 = *(const g2*)(s + 12);
    rA4 = s[14];
    if (lane < 32) {
      const float* s2 = baseB + (size_t)t0 * IN;
      rB0 = *(const g4*)(s2);     rB1 = *(const g4*)(s2 + 4);
      rB2 = *(const g4*)(s2 + 8); rB3 = *(const g2*)(s2 + 12);
      rB4 = s2[14];
    }
  };
  auto commit = [&](int bsel) {  // f32 regs -> f16 LDS rows (2x b128 each)
    v8h lo = {(_Float16)rA0.x, (_Float16)rA0.y, (_Float16)rA0.z, (_Float16)rA0.w,
              (_Float16)rA1.x, (_Float16)rA1.y, (_Float16)rA1.z, (_Float16)rA1.w};
    v8h hi = {(_Float16)rA2.x, (_Float16)rA2.y, (_Float16)rA2.z, (_Float16)rA2.w,
              (_Float16)rA3.x, (_Float16)rA3.y, (_Float16)rA4,   (_Float16)0.f};
    _Float16* d = xh + bsel * XBUF + grA * XGRP + tcA * XROW;
    *(v8h*)d = lo; *((v8h*)d + 1) = hi;
    if (lane < 32) {
      v8h lo2 = {(_Float16)rB0.x, (_Float16)rB0.y, (_Float16)rB0.z, (_Float16)rB0.w,
                 (_Float16)rB1.x, (_Float16)rB1.y, (_Float16)rB1.z, (_Float16)rB1.w};
      v8h hi2 = {(_Float16)rB2.x, (_Float16)rB2.y, (_Float16)rB2.z, (_Float16)rB2.w,
                 (_Float16)rB3.x, (_Float16)rB3.y, (_Float16)rB4,   (_Float16)0.f};
      _Float16* d2 = xh + bsel * XBUF + 2 * XGRP + tcA * XROW;
      *(v8h*)d2 = lo2; *((v8h*)d2 + 1) = hi2;
    }
  };

  issue(0);
  commit(0);

  float hn = 0.f;
  const _Float16* hrd = hh + g * HROW;
  _Float16* hwr = hh + g * HROW + j;
  for (int c = 0; c < NCH; ++c) {
    if (c + 1 < NCH) issue((c + 1) * CH);   // prefetch next chunk (global)
    const _Float16* xg = xh + (c & 1) * XBUF + gx * XGRP;
#pragma unroll 4
    for (int tc = 0; tc < CH; ++tc) {
      // h first in the DS queue (it's the critical path), then x.
      v8h ha = *(const v8h*)hrd;
      v8h hb = *(const v8h*)(hrd + 8);
      v4h hc = *(const v4h*)(hrd + 16);
      const v8h* xp = (const v8h*)(xg + tc * XROW);
      v8h xa = xp[0], xb = xp[1];
      float a0 = bias, a1 = 0.f, a2 = 0.f, a3 = 0.f;
      // x projection: 8 dot2 (pad half * wih[7].y=0)
      FD(a0, P2(xa, 0), wih[0]); FD(a1, P2(xa, 1), wih[1]);
      FD(a2, P2(xa, 2), wih[2]); FD(a3, P2(xa, 3), wih[3]);
      FD(a0, P2(xb, 0), wih[4]); FD(a1, P2(xb, 1), wih[5]);
      FD(a2, P2(xb, 2), wih[6]); FD(a3, P2(xb, 3), wih[7]);
      // recurrent projection: 10 dot2
      FD(a0, P2(ha, 0), whh[0]); FD(a1, P2(ha, 1), whh[1]);
      FD(a2, P2(ha, 2), whh[2]); FD(a3, P2(ha, 3), whh[3]);
      FD(a0, P2(hb, 0), whh[4]); FD(a1, P2(hb, 1), whh[5]);
      FD(a2, P2(hb, 2), whh[6]); FD(a3, P2(hb, 3), whh[7]);
      FD(a0, P2(hc, 0), whh[8]); FD(a1, P2(hc, 1), whh[9]);
      float s = (a0 + a1) + (a2 + a3);
      // tanh(s) = 1 - 2/(1+e^{2s})
      float e = exp2f(s * 2.8853900817779268f);
      hn = 1.f - 2.f * __builtin_amdgcn_rcpf(1.f + e);
      *hwr = (_Float16)hn;   // same-wave LDS, in-order DS pipe: no barrier
    }
    if (c + 1 < NCH) commit((c + 1) & 1);
  }
  if (g < 3 && b < B) out[(size_t)b * HD + j] = hn;
}

extern "C" void kernel_launch(void* const* d_in, const int* in_sizes, int n_in,
                              void* d_out, int out_size, void* d_ws, size_t ws_size,
                              hipStream_t stream) {
  const float* feature = (const float*)d_in[0];
  const float* W_ih    = (const float*)d_in[1];
  const float* W_hh    = (const float*)d_in[2];
  const float* b_ih    = (const float*)d_in[3];
  const float* b_hh    = (const float*)d_in[4];
  float* out = (float*)d_out;
  const int B = in_sizes[0] / (TT * IN);      // 4096
  const int grid = (B + 2) / 3;               // 3 batches per 64-thread block
  rnn_fused<<<grid, 64, 0, stream>>>(feature, W_ih, W_hh, b_ih, b_hh, out, B);
}